// Round 2
// baseline (682.358 us; speedup 1.0000x reference)
//
#include <hip/hip_runtime.h>

#define EPS 1e-5f

typedef float float8_t __attribute__((ext_vector_type(8)));
typedef float f32x4 __attribute__((ext_vector_type(4)));
typedef short short8_t __attribute__((ext_vector_type(8)));
typedef unsigned short ushort_t;

// ---------------- prep: fold BN(+bias) into scale/shift, build bf16 B-fragments ----------------
// prm layout (floats): [0..31] s1, [32..63] sh1, [64..127] s2, [128..191] sh2,
//                      [192..703] s3, [704..1215] sh3
// w2frag layout (bf16/ushort): [kk=25][nt=4][lane=64][j=8]
//   oc = nt*16 + (lane&15), ic = (lane>>4)*8 + j  (slot->k map matches A-frag builder)
__global__ void prep_kernel(const float* __restrict__ b1, const float* __restrict__ g1,
                            const float* __restrict__ be1, const float* __restrict__ m1,
                            const float* __restrict__ v1,
                            const float* __restrict__ b2, const float* __restrict__ g2,
                            const float* __restrict__ be2, const float* __restrict__ m2,
                            const float* __restrict__ v2,
                            const float* __restrict__ b3, const float* __restrict__ g3,
                            const float* __restrict__ be3, const float* __restrict__ m3,
                            const float* __restrict__ v3,
                            const float* __restrict__ w2, ushort_t* __restrict__ w2frag,
                            float* __restrict__ prm) {
  int tid = blockIdx.x * blockDim.x + threadIdx.x;
  int stride = gridDim.x * blockDim.x;
  for (int c = tid; c < 32; c += stride) {
    float s = g1[c] / sqrtf(v1[c] + EPS);
    prm[c] = s;
    prm[32 + c] = (b1[c] - m1[c]) * s + be1[c];
  }
  for (int c = tid; c < 64; c += stride) {
    float s = g2[c] / sqrtf(v2[c] + EPS);
    prm[64 + c] = s;
    prm[128 + c] = (b2[c] - m2[c]) * s + be2[c];
  }
  for (int c = tid; c < 512; c += stride) {
    float s = g3[c] / sqrtf(v3[c] + EPS);
    prm[192 + c] = s;
    prm[704 + c] = (b3[c] - m3[c]) * s + be3[c];
  }
  // w2: [64][32][5][5]; ternary -> bf16 truncation is exact for {-1,0,+1}
  for (int i = tid; i < 25 * 4 * 64 * 8; i += stride) {
    const int kk = i >> 11;
    const int r = i & 2047;
    const int nt = r >> 9;
    const int r2 = r & 511;
    const int l = r2 >> 3;
    const int j = r2 & 7;
    const int oc = nt * 16 + (l & 15);
    const int ic = (l >> 4) * 8 + j;
    const float v = w2[oc * 800 + ic * 25 + kk];
    w2frag[i] = (ushort_t)(__float_as_uint(v) >> 16);
  }
}

__device__ __forceinline__ void f32_to_bf16_hl(float v, ushort_t& hi, ushort_t& lo) {
  unsigned u = __float_as_uint(v);
  hi = (ushort_t)(u >> 16);
  float vh = __uint_as_float((unsigned)hi << 16);
  lo = (ushort_t)(__float_as_uint(v - vh) >> 16);
}

// ---------------- fused conv1+bn1+relu+pool1 + conv2(MFMA)+bn2+relu+pool2 ----------------
// one block per image, 256 threads = 4 waves.
// LDS ins layout: 144 cells (12x12 pooled grid), each cell = 32 ics as 4 chunks of
// 8 bf16 (16B). chunk slot swizzled: slot = (chunk + (cell>>1)) & 3.
__launch_bounds__(256)
__global__ void conv12_kernel(const float* __restrict__ x, const float* __restrict__ w1,
                              const ushort_t* __restrict__ w2frag,
                              const float* __restrict__ prm, float* __restrict__ h2p) {
  __shared__ float img[784];                 // 28x28 input image
  __shared__ __align__(32) float wl[800];    // w1 relaid: [k=25][oc=32]
  __shared__ short8_t insH8[576];            // hi bf16: 144 cells x 4 chunks
  __shared__ short8_t insL8[576];            // lo bf16
  __shared__ float p1[64];                   // s1|sh1
  __shared__ float p2[128];                  // s2|sh2

  const int b = blockIdx.x;
  const int tid = threadIdx.x;

  const float4* xin = (const float4*)(x + (size_t)b * 784);
  for (int i = tid; i < 196; i += 256) ((float4*)img)[i] = xin[i];
  for (int i = tid; i < 800; i += 256) {
    const int k = i >> 5, oc = i & 31;
    wl[i] = w1[oc * 25 + k];
  }
  if (tid < 64) p1[tid] = prm[tid];
  if (tid < 128) p2[tid] = prm[64 + tid];
  __syncthreads();

  const int w = tid >> 6;   // wave id 0..3
  const int l = tid & 63;   // lane

  // ---- conv1: wave w -> ocs [w*8, w*8+8). lane = one pre-pool pixel, 9 exact iters.
  // pixel order q = p_pool*4 + dy*2 + dx so 2x2 pool = shfl_xor 1,2.
  {
    const float8_t* wl8 = (const float8_t*)wl;   // [k=25][chunk=4]
    const float s_arr0 = p1[w * 8 + 0];
#pragma unroll 1
    for (int i = 0; i < 9; ++i) {
      const int q = i * 64 + l;
      const int p_pool = q >> 2;
      const int sub = q & 3;
      const int py = p_pool / 12;
      const int px = p_pool - py * 12;
      const int Y = 2 * py + (sub >> 1);
      const int X = 2 * px + (sub & 1);
      const int base = Y * 28 + X;
      float acc[8] = {0.f, 0.f, 0.f, 0.f, 0.f, 0.f, 0.f, 0.f};
#pragma unroll
      for (int ky = 0; ky < 5; ++ky) {
#pragma unroll
        for (int kx = 0; kx < 5; ++kx) {
          const float iv = img[base + ky * 28 + kx];
          const float8_t wv = wl8[(ky * 5 + kx) * 4 + w];
#pragma unroll
          for (int j = 0; j < 8; ++j) acc[j] = fmaf(iv, wv[j], acc[j]);
        }
      }
      short8_t hi8, lo8;
#pragma unroll
      for (int j = 0; j < 8; ++j) {
        const int oc = w * 8 + j;
        float v = fmaxf(fmaf(acc[j], p1[oc], p1[32 + oc]), 0.f);
        v = fmaxf(v, __shfl_xor(v, 1));
        v = fmaxf(v, __shfl_xor(v, 2));
        ushort_t h, lo;
        f32_to_bf16_hl(v, h, lo);
        hi8[j] = (short)h;
        lo8[j] = (short)lo;
      }
      if (sub == 0) {
        const int slot = p_pool * 4 + ((w + (p_pool >> 1)) & 3);
        insH8[slot] = hi8;
        insL8[slot] = lo8;
      }
    }
  }
  __syncthreads();

  // ---- conv2 via MFMA: wave w owns output pixels p = w*16 .. w*16+15 (M-tile),
  // 4 N-tiles of 16 ocs. A hi/lo split, B exact bf16. 25 taps x K=32 ics.
  {
    const int p = w * 16 + (l & 15);
    const int g = l >> 4;                  // k-group: ics g*8..g*8+7
    const int pb = (p >> 3) * 12 + (p & 7);
    f32x4 acc[4];
#pragma unroll
    for (int nt = 0; nt < 4; ++nt) acc[nt] = (f32x4){0.f, 0.f, 0.f, 0.f};

#pragma unroll
    for (int ky = 0; ky < 5; ++ky) {
#pragma unroll
      for (int kx = 0; kx < 5; ++kx) {
        const int c = pb + ky * 12 + kx;
        const int slot = c * 4 + ((g + (c >> 1)) & 3);
        const short8_t aH = insH8[slot];
        const short8_t aL = insL8[slot];
        const int kk = ky * 5 + kx;
        const ushort_t* wp = w2frag + ((size_t)kk * 4) * 512 + l * 8;
        const short8_t b0 = *(const short8_t*)(wp);
        const short8_t b1 = *(const short8_t*)(wp + 512);
        const short8_t b2 = *(const short8_t*)(wp + 1024);
        const short8_t b3 = *(const short8_t*)(wp + 1536);
        acc[0] = __builtin_amdgcn_mfma_f32_16x16x32_bf16(aH, b0, acc[0], 0, 0, 0);
        acc[0] = __builtin_amdgcn_mfma_f32_16x16x32_bf16(aL, b0, acc[0], 0, 0, 0);
        acc[1] = __builtin_amdgcn_mfma_f32_16x16x32_bf16(aH, b1, acc[1], 0, 0, 0);
        acc[1] = __builtin_amdgcn_mfma_f32_16x16x32_bf16(aL, b1, acc[1], 0, 0, 0);
        acc[2] = __builtin_amdgcn_mfma_f32_16x16x32_bf16(aH, b2, acc[2], 0, 0, 0);
        acc[2] = __builtin_amdgcn_mfma_f32_16x16x32_bf16(aL, b2, acc[2], 0, 0, 0);
        acc[3] = __builtin_amdgcn_mfma_f32_16x16x32_bf16(aH, b3, acc[3], 0, 0, 0);
        acc[3] = __builtin_amdgcn_mfma_f32_16x16x32_bf16(aL, b3, acc[3], 0, 0, 0);
      }
    }

    // epilogue: C/D layout col=lane&15 (oc), row=(lane>>4)*4+reg (pixel).
    // rows r,r+1 = horizontally adjacent pixels -> in-lane max; vertical pair = xor 32.
#pragma unroll
    for (int nt = 0; nt < 4; ++nt) {
      const int oc = nt * 16 + (l & 15);
      const float s = p2[oc], sh = p2[64 + oc];
      const float a0 = fmaxf(fmaf(acc[nt][0], s, sh), 0.f);
      const float a1 = fmaxf(fmaf(acc[nt][1], s, sh), 0.f);
      const float a2 = fmaxf(fmaf(acc[nt][2], s, sh), 0.f);
      const float a3v = fmaxf(fmaf(acc[nt][3], s, sh), 0.f);
      float m01 = fmaxf(a0, a1);
      float m23 = fmaxf(a2, a3v);
      m01 = fmaxf(m01, __shfl_xor(m01, 32));
      m23 = fmaxf(m23, __shfl_xor(m23, 32));
      if (l < 32) {
        const int px0 = (g & 1) * 2;   // g in {0,1} here
        float* dst = h2p + (size_t)b * 1024 + oc * 16 + w * 4;
        dst[px0] = m01;
        dst[px0 + 1] = m23;
      }
    }
  }
}

// ---------------- fc3 (1024->512) + bn3 + relu, tiled fp32 GEMM ----------------
__launch_bounds__(256)
__global__ void fc3_kernel(const float* __restrict__ h2p, const float* __restrict__ w3,
                           const float* __restrict__ prm, float* __restrict__ a3) {
  __shared__ float As[32][68];
  __shared__ float Bs[32][68];
  const int n0 = blockIdx.x * 64;
  const int m0 = blockIdx.y * 64;
  const int tid = threadIdx.x;
  const int tx = tid & 15, ty = tid >> 4;

  float c[4][4] = {{0.f}};

  for (int k0 = 0; k0 < 1024; k0 += 32) {
    for (int t = tid; t < 1024; t += 256) {
      const int isB = t >> 9;
      const int u = t & 511;
      const int r = u >> 3, c4 = u & 7;
      const float* src = isB ? (w3 + (size_t)(n0 + r) * 1024 + k0 + c4 * 4)
                             : (h2p + (size_t)(m0 + r) * 1024 + k0 + c4 * 4);
      const float4 v = *(const float4*)src;
      float(*dst)[68] = isB ? Bs : As;
      dst[c4 * 4 + 0][r] = v.x;
      dst[c4 * 4 + 1][r] = v.y;
      dst[c4 * 4 + 2][r] = v.z;
      dst[c4 * 4 + 3][r] = v.w;
    }
    __syncthreads();
#pragma unroll
    for (int k = 0; k < 32; ++k) {
      const float4 a = *(const float4*)&As[k][ty * 4];
      const float4 bb = *(const float4*)&Bs[k][tx * 4];
      const float av[4] = {a.x, a.y, a.z, a.w};
      const float bv[4] = {bb.x, bb.y, bb.z, bb.w};
#pragma unroll
      for (int i = 0; i < 4; ++i)
#pragma unroll
        for (int j = 0; j < 4; ++j) c[i][j] = fmaf(av[i], bv[j], c[i][j]);
    }
    __syncthreads();
  }

  const int n = n0 + tx * 4;
  float s[4], sh[4];
#pragma unroll
  for (int j = 0; j < 4; ++j) {
    s[j] = prm[192 + n + j];
    sh[j] = prm[704 + n + j];
  }
#pragma unroll
  for (int i = 0; i < 4; ++i) {
    const int m = m0 + ty * 4 + i;
    float4 o;
    o.x = fmaxf(fmaf(c[i][0], s[0], sh[0]), 0.f);
    o.y = fmaxf(fmaf(c[i][1], s[1], sh[1]), 0.f);
    o.z = fmaxf(fmaf(c[i][2], s[2], sh[2]), 0.f);
    o.w = fmaxf(fmaf(c[i][3], s[3], sh[3]), 0.f);
    *(float4*)(a3 + (size_t)m * 512 + n) = o;
  }
}

// ---------------- fc4 (512->10), one wave per batch row ----------------
__launch_bounds__(256)
__global__ void fc4_kernel(const float* __restrict__ a3, const float* __restrict__ w4,
                           float* __restrict__ out, int B) {
  const int w = threadIdx.x >> 6, l = threadIdx.x & 63;
  const int b = blockIdx.x * 4 + w;
  if (b >= B) return;
  const float4* ar = (const float4*)(a3 + (size_t)b * 512);
  const float4 a0 = ar[l * 2];
  const float4 a1 = ar[l * 2 + 1];
#pragma unroll
  for (int j = 0; j < 10; ++j) {
    const float4* wr = (const float4*)(w4 + j * 512);
    const float4 w0 = wr[l * 2];
    const float4 w1 = wr[l * 2 + 1];
    float sv = a0.x * w0.x + a0.y * w0.y + a0.z * w0.z + a0.w * w0.w +
               a1.x * w1.x + a1.y * w1.y + a1.z * w1.z + a1.w * w1.w;
#pragma unroll
    for (int off = 1; off < 64; off <<= 1) sv += __shfl_xor(sv, off);
    if (l == 0) out[(size_t)b * 10 + j] = sv;
  }
}

extern "C" void kernel_launch(void* const* d_in, const int* in_sizes, int n_in,
                              void* d_out, int out_size, void* d_ws, size_t ws_size,
                              hipStream_t stream) {
  const float* x  = (const float*)d_in[0];
  const float* w1 = (const float*)d_in[1];
  const float* b1 = (const float*)d_in[2];
  const float* g1 = (const float*)d_in[3];
  const float* be1 = (const float*)d_in[4];
  const float* m1 = (const float*)d_in[5];
  const float* v1 = (const float*)d_in[6];
  const float* w2 = (const float*)d_in[7];
  const float* b2 = (const float*)d_in[8];
  const float* g2 = (const float*)d_in[9];
  const float* be2 = (const float*)d_in[10];
  const float* m2 = (const float*)d_in[11];
  const float* v2 = (const float*)d_in[12];
  const float* w3 = (const float*)d_in[13];
  const float* b3 = (const float*)d_in[14];
  const float* g3 = (const float*)d_in[15];
  const float* be3 = (const float*)d_in[16];
  const float* m3 = (const float*)d_in[17];
  const float* v3 = (const float*)d_in[18];
  const float* w4 = (const float*)d_in[19];

  const int B = in_sizes[0] / 784;  // 8192

  float* ws = (float*)d_ws;
  float* h2p = ws;                              // B*1024 f32
  float* a3  = h2p + (size_t)B * 1024;          // B*512 f32
  float* prm = a3 + (size_t)B * 512;            // 1216 f32
  ushort_t* w2frag = (ushort_t*)(prm + 1216);   // 51200 bf16

  prep_kernel<<<64, 256, 0, stream>>>(b1, g1, be1, m1, v1, b2, g2, be2, m2, v2,
                                      b3, g3, be3, m3, v3, w2, w2frag, prm);
  conv12_kernel<<<B, 256, 0, stream>>>(x, w1, w2frag, prm, h2p);
  dim3 g3d(8, B / 64);
  fc3_kernel<<<g3d, 256, 0, stream>>>(h2p, w3, prm, a3);
  fc4_kernel<<<(B + 3) / 4, 256, 0, stream>>>(a3, w4, (float*)d_out, B);
}

// Round 3
// 636.498 us; speedup vs baseline: 1.0721x; 1.0721x over previous
//
#include <hip/hip_runtime.h>

#define EPS 1e-5f

typedef float float8_t __attribute__((ext_vector_type(8)));
typedef float f32x4 __attribute__((ext_vector_type(4)));
typedef short short8_t __attribute__((ext_vector_type(8)));
typedef unsigned short ushort_t;

// ---------------- prep: fold BN(+bias), build bf16 weight fragments ----------------
// prm layout (floats): [0..31] s1, [32..63] sh1, [64..127] s2, [128..191] sh2,
//                      [192..703] s3, [704..1215] sh3
// w2frag (ushort): [kk=25][nt=4][lane=64][j=8]; oc=nt*16+(l&15), ic=(l>>4)*8+j
// w3frag (ushort): [ks=32][ntg=32][lane=64][j=8]; oc=ntg*16+(l&15), k=ks*32+(l>>4)*8+j
__global__ void prep_kernel(const float* __restrict__ b1, const float* __restrict__ g1,
                            const float* __restrict__ be1, const float* __restrict__ m1,
                            const float* __restrict__ v1,
                            const float* __restrict__ b2, const float* __restrict__ g2,
                            const float* __restrict__ be2, const float* __restrict__ m2,
                            const float* __restrict__ v2,
                            const float* __restrict__ b3, const float* __restrict__ g3,
                            const float* __restrict__ be3, const float* __restrict__ m3,
                            const float* __restrict__ v3,
                            const float* __restrict__ w2, const float* __restrict__ w3,
                            ushort_t* __restrict__ w2frag, ushort_t* __restrict__ w3frag,
                            float* __restrict__ prm) {
  int tid = blockIdx.x * blockDim.x + threadIdx.x;
  int stride = gridDim.x * blockDim.x;
  for (int c = tid; c < 32; c += stride) {
    float s = g1[c] / sqrtf(v1[c] + EPS);
    prm[c] = s;
    prm[32 + c] = (b1[c] - m1[c]) * s + be1[c];
  }
  for (int c = tid; c < 64; c += stride) {
    float s = g2[c] / sqrtf(v2[c] + EPS);
    prm[64 + c] = s;
    prm[128 + c] = (b2[c] - m2[c]) * s + be2[c];
  }
  for (int c = tid; c < 512; c += stride) {
    float s = g3[c] / sqrtf(v3[c] + EPS);
    prm[192 + c] = s;
    prm[704 + c] = (b3[c] - m3[c]) * s + be3[c];
  }
  // w2: [64][32][5][5]; ternary -> bf16 truncation exact for {-1,0,+1}
  for (int i = tid; i < 25 * 4 * 64 * 8; i += stride) {
    const int kk = i >> 11;
    const int r = i & 2047;
    const int nt = r >> 9;
    const int r2 = r & 511;
    const int l = r2 >> 3;
    const int j = r2 & 7;
    const int oc = nt * 16 + (l & 15);
    const int ic = (l >> 4) * 8 + j;
    w2frag[i] = (ushort_t)(__float_as_uint(w2[oc * 800 + ic * 25 + kk]) >> 16);
  }
  // w3: [512][1024] ternary
  for (int i = tid; i < 32 * 32 * 64 * 8; i += stride) {
    const int ks = i >> 14;
    const int r = i & 16383;
    const int ntg = r >> 9;
    const int r2 = r & 511;
    const int l = r2 >> 3;
    const int j = r2 & 7;
    const int oc = ntg * 16 + (l & 15);
    const int k = ks * 32 + (l >> 4) * 8 + j;
    w3frag[i] = (ushort_t)(__float_as_uint(w3[oc * 1024 + k]) >> 16);
  }
}

__device__ __forceinline__ void f32_to_bf16_hl(float v, ushort_t& hi, ushort_t& lo) {
  unsigned u = __float_as_uint(v);
  hi = (ushort_t)(u >> 16);
  float vh = __uint_as_float((unsigned)hi << 16);
  lo = (ushort_t)(__float_as_uint(v - vh) >> 16);
}

// ---------------- fused conv1+bn1+relu+pool1 + conv2(MFMA)+bn2+relu+pool2 ----------------
// one block per image, 256 threads = 4 waves. Wave w owns N-tile w (ocs w*16..w*16+15)
// with its 25 B-fragments register-resident; loops 4 M-subtiles of 16 pixels from LDS.
__launch_bounds__(256)
__global__ void conv12_kernel(const float* __restrict__ x, const float* __restrict__ w1,
                              const ushort_t* __restrict__ w2frag,
                              const float* __restrict__ prm,
                              ushort_t* __restrict__ h2pH, ushort_t* __restrict__ h2pL) {
  __shared__ float img[784];
  __shared__ __align__(32) float wl[800];    // w1 relaid: [k=25][oc=32]
  __shared__ short8_t insH8[576];            // hi bf16: 144 cells x 4 chunks (swizzled)
  __shared__ short8_t insL8[576];
  __shared__ float p1[64];
  __shared__ float p2[128];

  const int b = blockIdx.x;
  const int tid = threadIdx.x;
  const int w = tid >> 6;
  const int l = tid & 63;

  // register-resident conv2 weights for this wave's N-tile (latency hides under conv1)
  short8_t wreg[25];
#pragma unroll
  for (int kk = 0; kk < 25; ++kk)
    wreg[kk] = *(const short8_t*)(w2frag + ((size_t)(kk * 4 + w)) * 512 + l * 8);

  const float4* xin = (const float4*)(x + (size_t)b * 784);
  for (int i = tid; i < 196; i += 256) ((float4*)img)[i] = xin[i];
  for (int i = tid; i < 800; i += 256) {
    const int k = i >> 5, oc = i & 31;
    wl[i] = w1[oc * 25 + k];
  }
  if (tid < 64) p1[tid] = prm[tid];
  if (tid < 128) p2[tid] = prm[64 + tid];
  __syncthreads();

  // ---- conv1: wave w -> conv1-ocs [w*8, w*8+8). lane = one pre-pool pixel, 9 iters.
  {
    const float8_t* wl8 = (const float8_t*)wl;
#pragma unroll 1
    for (int i = 0; i < 9; ++i) {
      const int q = i * 64 + l;
      const int p_pool = q >> 2;
      const int sub = q & 3;
      const int py = p_pool / 12;
      const int px = p_pool - py * 12;
      const int Y = 2 * py + (sub >> 1);
      const int X = 2 * px + (sub & 1);
      const int base = Y * 28 + X;
      float acc[8] = {0.f, 0.f, 0.f, 0.f, 0.f, 0.f, 0.f, 0.f};
#pragma unroll
      for (int ky = 0; ky < 5; ++ky) {
#pragma unroll
        for (int kx = 0; kx < 5; ++kx) {
          const float iv = img[base + ky * 28 + kx];
          const float8_t wv = wl8[(ky * 5 + kx) * 4 + w];
#pragma unroll
          for (int j = 0; j < 8; ++j) acc[j] = fmaf(iv, wv[j], acc[j]);
        }
      }
      short8_t hi8, lo8;
#pragma unroll
      for (int j = 0; j < 8; ++j) {
        const int oc = w * 8 + j;
        float v = fmaxf(fmaf(acc[j], p1[oc], p1[32 + oc]), 0.f);
        v = fmaxf(v, __shfl_xor(v, 1));
        v = fmaxf(v, __shfl_xor(v, 2));
        ushort_t h, lo;
        f32_to_bf16_hl(v, h, lo);
        hi8[j] = (short)h;
        lo8[j] = (short)lo;
      }
      if (sub == 0) {
        const int slot = p_pool * 4 + ((w + (p_pool >> 1)) & 3);
        insH8[slot] = hi8;
        insL8[slot] = lo8;
      }
    }
  }
  __syncthreads();

  // ---- conv2 via MFMA: all reads from LDS, weights from registers ----
  {
    const int g = l >> 4;
    const int m = l & 15;
    const int oc = w * 16 + m;
    const float s = p2[oc], sh = p2[64 + oc];
#pragma unroll 1
    for (int mt = 0; mt < 4; ++mt) {
      const int p = mt * 16 + m;
      const int pb = (p >> 3) * 12 + (p & 7);
      f32x4 accH = {0.f, 0.f, 0.f, 0.f};
      f32x4 accL = {0.f, 0.f, 0.f, 0.f};
#pragma unroll
      for (int ky = 0; ky < 5; ++ky) {
#pragma unroll
        for (int kx = 0; kx < 5; ++kx) {
          const int c = pb + ky * 12 + kx;
          const int slot = c * 4 + ((g + (c >> 1)) & 3);
          const int kk = ky * 5 + kx;
          accH = __builtin_amdgcn_mfma_f32_16x16x32_bf16(insH8[slot], wreg[kk], accH, 0, 0, 0);
          accL = __builtin_amdgcn_mfma_f32_16x16x32_bf16(insL8[slot], wreg[kk], accL, 0, 0, 0);
        }
      }
      // epilogue: C col=oc (l&15), row=(l>>4)*4+reg = pixel-in-subtile
      const float a0 = fmaxf(fmaf(accH[0] + accL[0], s, sh), 0.f);
      const float a1 = fmaxf(fmaf(accH[1] + accL[1], s, sh), 0.f);
      const float a2 = fmaxf(fmaf(accH[2] + accL[2], s, sh), 0.f);
      const float a3v = fmaxf(fmaf(accH[3] + accL[3], s, sh), 0.f);
      float m01 = fmaxf(a0, a1);
      float m23 = fmaxf(a2, a3v);
      m01 = fmaxf(m01, __shfl_xor(m01, 32));
      m23 = fmaxf(m23, __shfl_xor(m23, 32));
      if (l < 32) {
        const int px0 = (g & 1) * 2;
        const size_t base = (size_t)b * 1024 + oc * 16 + mt * 4 + px0;
        ushort_t h0, l0, h1, l1;
        f32_to_bf16_hl(m01, h0, l0);
        f32_to_bf16_hl(m23, h1, l1);
        h2pH[base] = h0;
        h2pL[base] = l0;
        h2pH[base + 1] = h1;
        h2pL[base + 1] = l1;
      }
    }
  }
}

// ---------------- fc3 (1024->512) + bn3 + relu via bf16 MFMA, no LDS ----------------
// grid: (8 N-tiles of 64, 128 M-tiles of 64), 256 threads = 4 waves (wave = 16 rows)
__launch_bounds__(256)
__global__ void fc3_kernel(const ushort_t* __restrict__ h2pH, const ushort_t* __restrict__ h2pL,
                           const ushort_t* __restrict__ w3frag, const float* __restrict__ prm,
                           float* __restrict__ a3) {
  const int n0 = blockIdx.x * 64;
  const int m0 = blockIdx.y * 64;
  const int w = threadIdx.x >> 6, l = threadIdx.x & 63;
  const int mrow = m0 + w * 16 + (l & 15);
  const int kc8 = (l >> 4) * 8;

  const ushort_t* aHp = h2pH + (size_t)mrow * 1024 + kc8;
  const ushort_t* aLp = h2pL + (size_t)mrow * 1024 + kc8;
  const ushort_t* bp = w3frag + (size_t)(n0 >> 4) * 512 + (size_t)l * 8;

  f32x4 accH[4], accL[4];
#pragma unroll
  for (int t = 0; t < 4; ++t) {
    accH[t] = (f32x4){0.f, 0.f, 0.f, 0.f};
    accL[t] = (f32x4){0.f, 0.f, 0.f, 0.f};
  }

#pragma unroll 2
  for (int ks = 0; ks < 32; ++ks) {
    const short8_t aH = *(const short8_t*)(aHp + ks * 32);
    const short8_t aL = *(const short8_t*)(aLp + ks * 32);
    const ushort_t* bks = bp + (size_t)ks * 16384;
#pragma unroll
    for (int t = 0; t < 4; ++t) {
      const short8_t bb = *(const short8_t*)(bks + t * 512);
      accH[t] = __builtin_amdgcn_mfma_f32_16x16x32_bf16(aH, bb, accH[t], 0, 0, 0);
      accL[t] = __builtin_amdgcn_mfma_f32_16x16x32_bf16(aL, bb, accL[t], 0, 0, 0);
    }
  }

#pragma unroll
  for (int t = 0; t < 4; ++t) {
    const int oc = n0 + t * 16 + (l & 15);
    const float s = prm[192 + oc], sh = prm[704 + oc];
#pragma unroll
    for (int r = 0; r < 4; ++r) {
      const int m = m0 + w * 16 + (l >> 4) * 4 + r;
      a3[(size_t)m * 512 + oc] = fmaxf(fmaf(accH[t][r] + accL[t][r], s, sh), 0.f);
    }
  }
}

// ---------------- fc4 (512->10), one wave per batch row ----------------
__launch_bounds__(256)
__global__ void fc4_kernel(const float* __restrict__ a3, const float* __restrict__ w4,
                           float* __restrict__ out, int B) {
  const int w = threadIdx.x >> 6, l = threadIdx.x & 63;
  const int b = blockIdx.x * 4 + w;
  if (b >= B) return;
  const float4* ar = (const float4*)(a3 + (size_t)b * 512);
  const float4 a0 = ar[l * 2];
  const float4 a1 = ar[l * 2 + 1];
#pragma unroll
  for (int j = 0; j < 10; ++j) {
    const float4* wr = (const float4*)(w4 + j * 512);
    const float4 w0 = wr[l * 2];
    const float4 w1 = wr[l * 2 + 1];
    float sv = a0.x * w0.x + a0.y * w0.y + a0.z * w0.z + a0.w * w0.w +
               a1.x * w1.x + a1.y * w1.y + a1.z * w1.z + a1.w * w1.w;
#pragma unroll
    for (int off = 1; off < 64; off <<= 1) sv += __shfl_xor(sv, off);
    if (l == 0) out[(size_t)b * 10 + j] = sv;
  }
}

extern "C" void kernel_launch(void* const* d_in, const int* in_sizes, int n_in,
                              void* d_out, int out_size, void* d_ws, size_t ws_size,
                              hipStream_t stream) {
  const float* x  = (const float*)d_in[0];
  const float* w1 = (const float*)d_in[1];
  const float* b1 = (const float*)d_in[2];
  const float* g1 = (const float*)d_in[3];
  const float* be1 = (const float*)d_in[4];
  const float* m1 = (const float*)d_in[5];
  const float* v1 = (const float*)d_in[6];
  const float* w2 = (const float*)d_in[7];
  const float* b2 = (const float*)d_in[8];
  const float* g2 = (const float*)d_in[9];
  const float* be2 = (const float*)d_in[10];
  const float* m2 = (const float*)d_in[11];
  const float* v2 = (const float*)d_in[12];
  const float* w3 = (const float*)d_in[13];
  const float* b3 = (const float*)d_in[14];
  const float* g3 = (const float*)d_in[15];
  const float* be3 = (const float*)d_in[16];
  const float* m3 = (const float*)d_in[17];
  const float* v3 = (const float*)d_in[18];
  const float* w4 = (const float*)d_in[19];

  const int B = in_sizes[0] / 784;  // 8192

  float* prm = (float*)d_ws;                          // 1216 f32
  ushort_t* w2frag = (ushort_t*)(prm + 1216);         // 51200
  ushort_t* w3frag = w2frag + 51200;                  // 524288
  ushort_t* h2pH = w3frag + 524288;                   // B*1024
  ushort_t* h2pL = h2pH + (size_t)B * 1024;           // B*1024
  float* a3 = (float*)(h2pL + (size_t)B * 1024);      // B*512 f32

  prep_kernel<<<64, 256, 0, stream>>>(b1, g1, be1, m1, v1, b2, g2, be2, m2, v2,
                                      b3, g3, be3, m3, v3, w2, w3, w2frag, w3frag, prm);
  conv12_kernel<<<B, 256, 0, stream>>>(x, w1, w2frag, prm, h2pH, h2pL);
  dim3 g3d(8, B / 64);
  fc3_kernel<<<g3d, 256, 0, stream>>>(h2pH, h2pL, w3frag, prm, a3);
  fc4_kernel<<<(B + 3) / 4, 256, 0, stream>>>(a3, w4, (float*)d_out, B);
}

// Round 4
// 602.398 us; speedup vs baseline: 1.1327x; 1.0566x over previous
//
#include <hip/hip_runtime.h>

#define EPS 1e-5f

typedef float float8_t __attribute__((ext_vector_type(8)));
typedef float f32x4 __attribute__((ext_vector_type(4)));
typedef short short8_t __attribute__((ext_vector_type(8)));
typedef unsigned short ushort_t;

// ---------------- prep: fold BN(+bias), build bf16 weight fragments ----------------
// prm (floats): [0..31] s1, [32..63] sh1, [64..127] s2, [128..191] sh2,
//               [192..703] s3, [704..1215] sh3
// w2frag (ushort): [kk=25][nt=4][lane=64][j=8]; oc=nt*16+(l&15), ic=(l>>4)*8+j
// w3frag (ushort): [ks=32][ntg=32][lane=64][j=8]; oc=ntg*16+(l&15), k=ks*32+(l>>4)*8+j
__global__ void prep_kernel(const float* __restrict__ b1, const float* __restrict__ g1,
                            const float* __restrict__ be1, const float* __restrict__ m1,
                            const float* __restrict__ v1,
                            const float* __restrict__ b2, const float* __restrict__ g2,
                            const float* __restrict__ be2, const float* __restrict__ m2,
                            const float* __restrict__ v2,
                            const float* __restrict__ b3, const float* __restrict__ g3,
                            const float* __restrict__ be3, const float* __restrict__ m3,
                            const float* __restrict__ v3,
                            const float* __restrict__ w2, const float* __restrict__ w3,
                            ushort_t* __restrict__ w2frag, ushort_t* __restrict__ w3frag,
                            float* __restrict__ prm) {
  int tid = blockIdx.x * blockDim.x + threadIdx.x;
  int stride = gridDim.x * blockDim.x;
  for (int c = tid; c < 32; c += stride) {
    float s = g1[c] / sqrtf(v1[c] + EPS);
    prm[c] = s;
    prm[32 + c] = (b1[c] - m1[c]) * s + be1[c];
  }
  for (int c = tid; c < 64; c += stride) {
    float s = g2[c] / sqrtf(v2[c] + EPS);
    prm[64 + c] = s;
    prm[128 + c] = (b2[c] - m2[c]) * s + be2[c];
  }
  for (int c = tid; c < 512; c += stride) {
    float s = g3[c] / sqrtf(v3[c] + EPS);
    prm[192 + c] = s;
    prm[704 + c] = (b3[c] - m3[c]) * s + be3[c];
  }
  // w2: [64][32][5][5]; ternary -> bf16 truncation exact for {-1,0,+1}
  for (int i = tid; i < 25 * 4 * 64 * 8; i += stride) {
    const int kk = i >> 11;
    const int r = i & 2047;
    const int nt = r >> 9;
    const int r2 = r & 511;
    const int l = r2 >> 3;
    const int j = r2 & 7;
    const int oc = nt * 16 + (l & 15);
    const int ic = (l >> 4) * 8 + j;
    w2frag[i] = (ushort_t)(__float_as_uint(w2[oc * 800 + ic * 25 + kk]) >> 16);
  }
  // w3: [512][1024] ternary
  for (int i = tid; i < 32 * 32 * 64 * 8; i += stride) {
    const int ks = i >> 14;
    const int r = i & 16383;
    const int ntg = r >> 9;
    const int r2 = r & 511;
    const int l = r2 >> 3;
    const int j = r2 & 7;
    const int oc = ntg * 16 + (l & 15);
    const int k = ks * 32 + (l >> 4) * 8 + j;
    w3frag[i] = (ushort_t)(__float_as_uint(w3[oc * 1024 + k]) >> 16);
  }
}

__device__ __forceinline__ void f32_to_bf16_hl(float v, ushort_t& hi, ushort_t& lo) {
  unsigned u = __float_as_uint(v);
  hi = (ushort_t)(u >> 16);
  float vh = __uint_as_float((unsigned)hi << 16);
  lo = (ushort_t)(__float_as_uint(v - vh) >> 16);
}

// ---------------- fused conv1+bn1+relu+pool1 + conv2(MFMA)+bn2+relu+pool2 ----------------
// Block = 2 images, 256 threads = 4 waves. Waves (0,1)->img0, (2,3)->img1.
// conv1: wave-half owns 16 conv1-ocs. conv2: wave-half owns 2 oc-tiles (32 ocs),
// weights register-resident in 2 tap-passes (13+12).
// ins LDS layout (short8 slots): [img2][plane2][g4][145]; slot=img*1160+plane*580+g*145+c
// byte = 16*(g+c) mod 128 across lanes -> bank-conflict-free b128 reads.
__launch_bounds__(256)
__global__ void conv12_kernel(const float* __restrict__ x, const float* __restrict__ w1,
                              const ushort_t* __restrict__ w2frag,
                              const float* __restrict__ prm,
                              ushort_t* __restrict__ h2pH, ushort_t* __restrict__ h2pL) {
  __shared__ float img[1568];                // 2 images 28x28 f32
  __shared__ __align__(32) float wl[800];    // w1 relaid: [k=25][oc=32]
  __shared__ short8_t ins8[2320];            // pooled conv1 out, bf16 hi/lo planes
  __shared__ float p1[64];
  __shared__ float p2[128];

  const int b = blockIdx.x;
  const int tid = threadIdx.x;
  const int w = tid >> 6;
  const int l = tid & 63;
  const int iw = w >> 1;     // image in block
  const int half = w & 1;    // oc-half

  // stage 2 images + conv1 weights + bn params
  const float4* xin = (const float4*)(x + (size_t)b * 1568);
  for (int i = tid; i < 392; i += 256) ((float4*)img)[i] = xin[i];
  for (int i = tid; i < 800; i += 256) {
    const int k = i >> 5, oc = i & 31;
    wl[i] = w1[oc * 25 + k];
  }
  if (tid < 64) p1[tid] = prm[tid];
  if (tid < 128) p2[tid] = prm[64 + tid];
  __syncthreads();

  // ---- conv1 (fp32 VALU): lane = one pre-pool pixel (q-order), 9 iters; 16 ocs/wave ----
  {
    const int ocb = half * 16;
    float sar[16], shr[16];
#pragma unroll
    for (int j = 0; j < 16; ++j) {
      sar[j] = p1[ocb + j];
      shr[j] = p1[32 + ocb + j];
    }
    const float8_t* wl8 = (const float8_t*)wl;
    const float* imgb = img + iw * 784;
    const int ibase = iw * 1160;
#pragma unroll 1
    for (int i = 0; i < 9; ++i) {
      const int q = i * 64 + l;
      const int p_pool = q >> 2;
      const int sub = q & 3;
      const int py = p_pool / 12;
      const int px = p_pool - py * 12;
      const int Y = 2 * py + (sub >> 1);
      const int X = 2 * px + (sub & 1);
      const int base = Y * 28 + X;
      float acc[16];
#pragma unroll
      for (int j = 0; j < 16; ++j) acc[j] = 0.f;
#pragma unroll
      for (int ky = 0; ky < 5; ++ky) {
#pragma unroll
        for (int kx = 0; kx < 5; ++kx) {
          const float iv = imgb[base + ky * 28 + kx];
          const float8_t wv0 = wl8[(ky * 5 + kx) * 4 + half * 2];
          const float8_t wv1 = wl8[(ky * 5 + kx) * 4 + half * 2 + 1];
#pragma unroll
          for (int j = 0; j < 8; ++j) {
            acc[j] = fmaf(iv, wv0[j], acc[j]);
            acc[8 + j] = fmaf(iv, wv1[j], acc[8 + j]);
          }
        }
      }
      short8_t h8[2], l8[2];
#pragma unroll
      for (int j = 0; j < 16; ++j) {
        float v = fmaxf(fmaf(acc[j], sar[j], shr[j]), 0.f);
        v = fmaxf(v, __shfl_xor(v, 1));
        v = fmaxf(v, __shfl_xor(v, 2));
        ushort_t hh, ll;
        f32_to_bf16_hl(v, hh, ll);
        h8[j >> 3][j & 7] = (short)hh;
        l8[j >> 3][j & 7] = (short)ll;
      }
      if (sub == 0) {
        const int c = p_pool;
        ins8[ibase + (half * 2) * 145 + c] = h8[0];
        ins8[ibase + (half * 2 + 1) * 145 + c] = h8[1];
        ins8[ibase + 580 + (half * 2) * 145 + c] = l8[0];
        ins8[ibase + 580 + (half * 2 + 1) * 145 + c] = l8[1];
      }
    }
  }
  __syncthreads();

  // ---- conv2 via MFMA: wave-half owns oc-tiles {ntb, ntb+1}; 2 weight passes ----
  {
    const int g = l >> 4;
    const int m = l & 15;
    const int ntb = half * 2;
    int bs[4];
#pragma unroll
    for (int mt = 0; mt < 4; ++mt) {
      const int p = mt * 16 + m;
      const int pb = (p >> 3) * 12 + (p & 7);
      bs[mt] = iw * 1160 + g * 145 + pb;
    }
    f32x4 acc[4][2];
#pragma unroll
    for (int mt = 0; mt < 4; ++mt)
#pragma unroll
      for (int n = 0; n < 2; ++n) acc[mt][n] = (f32x4){0.f, 0.f, 0.f, 0.f};

#pragma unroll
    for (int pass = 0; pass < 2; ++pass) {
      const int t0 = pass ? 13 : 0;
      const int NT = pass ? 12 : 13;
      short8_t wreg[13][2];
#pragma unroll
      for (int t = 0; t < 13; ++t) {
        if (t < NT) {
          const short8_t* wp = (const short8_t*)w2frag + ((t0 + t) * 4 + ntb) * 64 + l;
          wreg[t][0] = wp[0];
          wreg[t][1] = wp[64];
        }
      }
#pragma unroll
      for (int t = 0; t < 13; ++t) {
        if (t < NT) {
          const int tap = t0 + t;
          const int koff = (tap / 5) * 12 + (tap % 5);
#pragma unroll
          for (int mt = 0; mt < 4; ++mt) {
            const short8_t aH = ins8[bs[mt] + koff];
            const short8_t aL = ins8[bs[mt] + 580 + koff];
#pragma unroll
            for (int n = 0; n < 2; ++n) {
              acc[mt][n] = __builtin_amdgcn_mfma_f32_16x16x32_bf16(aH, wreg[t][n], acc[mt][n], 0, 0, 0);
              acc[mt][n] = __builtin_amdgcn_mfma_f32_16x16x32_bf16(aL, wreg[t][n], acc[mt][n], 0, 0, 0);
            }
          }
        }
      }
    }

    // epilogue: C col=oc (l&15), row=(l>>4)*4+reg = pixel-in-subtile (raster 8x8)
    const size_t ob = (size_t)(b * 2 + iw) * 1024;
#pragma unroll
    for (int mt = 0; mt < 4; ++mt) {
#pragma unroll
      for (int n = 0; n < 2; ++n) {
        const int oc = (ntb + n) * 16 + m;
        const float s = p2[oc], sh = p2[64 + oc];
        const float a0 = fmaxf(fmaf(acc[mt][n][0], s, sh), 0.f);
        const float a1 = fmaxf(fmaf(acc[mt][n][1], s, sh), 0.f);
        const float a2 = fmaxf(fmaf(acc[mt][n][2], s, sh), 0.f);
        const float a3v = fmaxf(fmaf(acc[mt][n][3], s, sh), 0.f);
        float m01 = fmaxf(a0, a1);
        float m23 = fmaxf(a2, a3v);
        m01 = fmaxf(m01, __shfl_xor(m01, 32));
        m23 = fmaxf(m23, __shfl_xor(m23, 32));
        if (l < 32) {
          const int px0 = (g & 1) * 2;
          const size_t obase = ob + oc * 16 + mt * 4 + px0;
          ushort_t h0, l0, h1, l1;
          f32_to_bf16_hl(m01, h0, l0);
          f32_to_bf16_hl(m23, h1, l1);
          *(unsigned*)(&h2pH[obase]) = (unsigned)h0 | ((unsigned)h1 << 16);
          *(unsigned*)(&h2pL[obase]) = (unsigned)l0 | ((unsigned)l1 << 16);
        }
      }
    }
  }
}

// ---------------- fc3 (1024->512) + bn3 + relu via bf16 MFMA, no LDS ----------------
// grid (8,128); XCD-chunked swizzle: the 8 N-blocks sharing an A-panel -> same XCD L2
__launch_bounds__(256)
__global__ void fc3_kernel(const ushort_t* __restrict__ h2pH, const ushort_t* __restrict__ h2pL,
                           const ushort_t* __restrict__ w3frag, const float* __restrict__ prm,
                           float* __restrict__ a3) {
  const int orig = blockIdx.x + (blockIdx.y << 3);
  const int xcd = orig & 7;
  const int j = orig >> 3;             // 0..127
  const int ytile = (xcd << 4) | (j >> 3);
  const int xtile = j & 7;
  const int n0 = xtile * 64;
  const int m0 = ytile * 64;
  const int w = threadIdx.x >> 6, l = threadIdx.x & 63;
  const int mrow = m0 + w * 16 + (l & 15);
  const int kc8 = (l >> 4) * 8;

  const ushort_t* aHp = h2pH + (size_t)mrow * 1024 + kc8;
  const ushort_t* aLp = h2pL + (size_t)mrow * 1024 + kc8;
  const ushort_t* bp = w3frag + (size_t)(n0 >> 4) * 512 + (size_t)l * 8;

  f32x4 accH[4], accL[4];
#pragma unroll
  for (int t = 0; t < 4; ++t) {
    accH[t] = (f32x4){0.f, 0.f, 0.f, 0.f};
    accL[t] = (f32x4){0.f, 0.f, 0.f, 0.f};
  }

#pragma unroll 2
  for (int ks = 0; ks < 32; ++ks) {
    const short8_t aH = *(const short8_t*)(aHp + ks * 32);
    const short8_t aL = *(const short8_t*)(aLp + ks * 32);
    const ushort_t* bks = bp + (size_t)ks * 16384;
#pragma unroll
    for (int t = 0; t < 4; ++t) {
      const short8_t bb = *(const short8_t*)(bks + t * 512);
      accH[t] = __builtin_amdgcn_mfma_f32_16x16x32_bf16(aH, bb, accH[t], 0, 0, 0);
      accL[t] = __builtin_amdgcn_mfma_f32_16x16x32_bf16(aL, bb, accL[t], 0, 0, 0);
    }
  }

#pragma unroll
  for (int t = 0; t < 4; ++t) {
    const int oc = n0 + t * 16 + (l & 15);
    const float s = prm[192 + oc], sh = prm[704 + oc];
#pragma unroll
    for (int r = 0; r < 4; ++r) {
      const int m = m0 + w * 16 + (l >> 4) * 4 + r;
      a3[(size_t)m * 512 + oc] = fmaxf(fmaf(accH[t][r] + accL[t][r], s, sh), 0.f);
    }
  }
}

// ---------------- fc4 (512->10), one wave per batch row ----------------
__launch_bounds__(256)
__global__ void fc4_kernel(const float* __restrict__ a3, const float* __restrict__ w4,
                           float* __restrict__ out, int B) {
  const int w = threadIdx.x >> 6, l = threadIdx.x & 63;
  const int b = blockIdx.x * 4 + w;
  if (b >= B) return;
  const float4* ar = (const float4*)(a3 + (size_t)b * 512);
  const float4 a0 = ar[l * 2];
  const float4 a1 = ar[l * 2 + 1];
#pragma unroll
  for (int j = 0; j < 10; ++j) {
    const float4* wr = (const float4*)(w4 + j * 512);
    const float4 w0 = wr[l * 2];
    const float4 w1 = wr[l * 2 + 1];
    float sv = a0.x * w0.x + a0.y * w0.y + a0.z * w0.z + a0.w * w0.w +
               a1.x * w1.x + a1.y * w1.y + a1.z * w1.z + a1.w * w1.w;
#pragma unroll
    for (int off = 1; off < 64; off <<= 1) sv += __shfl_xor(sv, off);
    if (l == 0) out[(size_t)b * 10 + j] = sv;
  }
}

extern "C" void kernel_launch(void* const* d_in, const int* in_sizes, int n_in,
                              void* d_out, int out_size, void* d_ws, size_t ws_size,
                              hipStream_t stream) {
  const float* x  = (const float*)d_in[0];
  const float* w1 = (const float*)d_in[1];
  const float* b1 = (const float*)d_in[2];
  const float* g1 = (const float*)d_in[3];
  const float* be1 = (const float*)d_in[4];
  const float* m1 = (const float*)d_in[5];
  const float* v1 = (const float*)d_in[6];
  const float* w2 = (const float*)d_in[7];
  const float* b2 = (const float*)d_in[8];
  const float* g2 = (const float*)d_in[9];
  const float* be2 = (const float*)d_in[10];
  const float* m2 = (const float*)d_in[11];
  const float* v2 = (const float*)d_in[12];
  const float* w3 = (const float*)d_in[13];
  const float* b3 = (const float*)d_in[14];
  const float* g3 = (const float*)d_in[15];
  const float* be3 = (const float*)d_in[16];
  const float* m3 = (const float*)d_in[17];
  const float* v3 = (const float*)d_in[18];
  const float* w4 = (const float*)d_in[19];

  const int B = in_sizes[0] / 784;  // 8192

  float* prm = (float*)d_ws;                          // 1216 f32
  ushort_t* w2frag = (ushort_t*)(prm + 1216);         // 51200
  ushort_t* w3frag = w2frag + 51200;                  // 524288
  ushort_t* h2pH = w3frag + 524288;                   // B*1024
  ushort_t* h2pL = h2pH + (size_t)B * 1024;           // B*1024
  float* a3 = (float*)(h2pL + (size_t)B * 1024);      // B*512 f32

  prep_kernel<<<64, 256, 0, stream>>>(b1, g1, be1, m1, v1, b2, g2, be2, m2, v2,
                                      b3, g3, be3, m3, v3, w2, w3, w2frag, w3frag, prm);
  conv12_kernel<<<B / 2, 256, 0, stream>>>(x, w1, w2frag, prm, h2pH, h2pL);
  dim3 g3d(8, B / 64);
  fc3_kernel<<<g3d, 256, 0, stream>>>(h2pH, h2pL, w3frag, prm, a3);
  fc4_kernel<<<(B + 3) / 4, 256, 0, stream>>>(a3, w4, (float*)d_out, B);
}

// Round 5
// 320.142 us; speedup vs baseline: 2.1314x; 1.8817x over previous
//
#include <hip/hip_runtime.h>

#define EPS 1e-5f

typedef float f32x4 __attribute__((ext_vector_type(4)));
typedef short short8_t __attribute__((ext_vector_type(8)));
typedef unsigned int uint4v __attribute__((ext_vector_type(4)));
typedef unsigned short ushort_t;

// ---------------- prep: fold BN(+bias), build bf16 weight fragments ----------------
// prm (floats): [0..31] s1, [32..63] sh1, [64..127] s2, [128..191] sh2,
//               [192..703] s3, [704..1215] sh3
// w1frag (ushort): [plane=2][nt=2][lane=64][j=8]; oc=nt*16+(l&15), tap=(l>>4)*8+j (0 if tap>=25)
// w2frag (ushort): [kk=25][nt=4][lane=64][j=8]; oc=nt*16+(l&15), ic=(l>>4)*8+j
// w3frag (ushort): [ks=32][ntg=32][lane=64][j=8]; oc=ntg*16+(l&15), k=ks*32+(l>>4)*8+j
__global__ void prep_kernel(const float* __restrict__ b1, const float* __restrict__ g1,
                            const float* __restrict__ be1, const float* __restrict__ m1,
                            const float* __restrict__ v1,
                            const float* __restrict__ b2, const float* __restrict__ g2,
                            const float* __restrict__ be2, const float* __restrict__ m2,
                            const float* __restrict__ v2,
                            const float* __restrict__ b3, const float* __restrict__ g3,
                            const float* __restrict__ be3, const float* __restrict__ m3,
                            const float* __restrict__ v3,
                            const float* __restrict__ w1, const float* __restrict__ w2,
                            const float* __restrict__ w3,
                            ushort_t* __restrict__ w1frag, ushort_t* __restrict__ w2frag,
                            ushort_t* __restrict__ w3frag, float* __restrict__ prm) {
  int tid = blockIdx.x * blockDim.x + threadIdx.x;
  int stride = gridDim.x * blockDim.x;
  for (int c = tid; c < 32; c += stride) {
    float s = g1[c] / sqrtf(v1[c] + EPS);
    prm[c] = s;
    prm[32 + c] = (b1[c] - m1[c]) * s + be1[c];
  }
  for (int c = tid; c < 64; c += stride) {
    float s = g2[c] / sqrtf(v2[c] + EPS);
    prm[64 + c] = s;
    prm[128 + c] = (b2[c] - m2[c]) * s + be2[c];
  }
  for (int c = tid; c < 512; c += stride) {
    float s = g3[c] / sqrtf(v3[c] + EPS);
    prm[192 + c] = s;
    prm[704 + c] = (b3[c] - m3[c]) * s + be3[c];
  }
  // w1frag: hi/lo planes (w1 is NOT ternary)
  for (int i = tid; i < 2 * 2 * 64 * 8; i += stride) {
    const int j = i & 7;
    const int l = (i >> 3) & 63;
    const int nt = (i >> 9) & 1;
    const int p = i >> 10;
    const int oc = nt * 16 + (l & 15);
    const int t = (l >> 4) * 8 + j;
    const float v = (t < 25) ? w1[oc * 25 + t] : 0.f;
    const unsigned u = __float_as_uint(v);
    const ushort_t hi = (ushort_t)(u >> 16);
    const float r = v - __uint_as_float(u & 0xffff0000u);
    const ushort_t lo = (ushort_t)(__float_as_uint(r) >> 16);
    w1frag[i] = p ? lo : hi;
  }
  // w2: [64][32][5][5]; ternary -> bf16 truncation exact
  for (int i = tid; i < 25 * 4 * 64 * 8; i += stride) {
    const int kk = i >> 11;
    const int r = i & 2047;
    const int nt = r >> 9;
    const int r2 = r & 511;
    const int l = r2 >> 3;
    const int j = r2 & 7;
    const int oc = nt * 16 + (l & 15);
    const int ic = (l >> 4) * 8 + j;
    w2frag[i] = (ushort_t)(__float_as_uint(w2[oc * 800 + ic * 25 + kk]) >> 16);
  }
  // w3: [512][1024] ternary
  for (int i = tid; i < 32 * 32 * 64 * 8; i += stride) {
    const int ks = i >> 14;
    const int r = i & 16383;
    const int ntg = r >> 9;
    const int r2 = r & 511;
    const int l = r2 >> 3;
    const int j = r2 & 7;
    const int oc = ntg * 16 + (l & 15);
    const int k = ks * 32 + (l >> 4) * 8 + j;
    w3frag[i] = (ushort_t)(__float_as_uint(w3[oc * 1024 + k]) >> 16);
  }
}

// ---------------- fused conv1+bn1+relu+pool1 + conv2+bn2+relu+pool2, all MFMA ----------------
// Block = 128 threads = 2 waves; each wave owns ONE image end-to-end (no barriers).
// Per-wave LDS arena (26240 B): imgf[800] f32 (3200 B) + insA 2 planes x 144 cells x 80 B.
// insA cell stride 80 B makes the conv2 ds_read_b128 pattern conflict-free/2-way.
// q-ordering (q = cell*4 + sub) makes each C-fragment's 4 regs = one 2x2 pool window.
__launch_bounds__(128)
__global__ void conv12_kernel(const float* __restrict__ x,
                              const ushort_t* __restrict__ w1frag,
                              const ushort_t* __restrict__ w2frag,
                              const float* __restrict__ prm,
                              ushort_t* __restrict__ h2pH, ushort_t* __restrict__ h2pL) {
  __shared__ __align__(16) unsigned char lds[52480];

  const int tid = threadIdx.x;
  const int w = tid >> 6, l = tid & 63;
  const int b = blockIdx.x * 2 + w;
  const int m15 = l & 15, g = l >> 4;

  unsigned char* arena = lds + w * 26240;
  float* imgf = (float*)arena;                          // 800 f32
  ushort_t* insA = (ushort_t*)(arena + 3200);           // 2 x 5760 ushorts (stride 40/cell)

  // --- stage this wave's image into LDS ---
  const float* xb = x + (size_t)b * 784;
#pragma unroll
  for (int it = 0; it < 4; ++it) {
    const int idx = it * 64 + l;
    if (idx < 196) ((float4*)imgf)[idx] = ((const float4*)xb)[idx];
  }
  if (l < 16) imgf[784 + l] = 0.f;

  // --- conv1 B-frags (hi/lo), 16 VGPRs total ---
  short8_t B1h[2], B1l[2];
#pragma unroll
  for (int nt = 0; nt < 2; ++nt) {
    B1h[nt] = *(const short8_t*)(w1frag + (size_t)(nt * 64 + l) * 8);
    B1l[nt] = *(const short8_t*)(w1frag + (size_t)((2 + nt) * 64 + l) * 8);
  }

  // per-lane tap offsets for this lane's k-group (fake taps clamped in-bounds; B=0 there)
  int off[8];
#pragma unroll
  for (int j = 0; j < 8; ++j) {
    const int t = g * 8 + j;
    const int ky = t / 5, kx = t - ky * 5;
    off[j] = (t < 25) ? (ky * 28 + kx) : 0;
  }

  // BN params in regs
  float s1[2], sh1[2], s2[4], sh2[4];
#pragma unroll
  for (int nt = 0; nt < 2; ++nt) {
    s1[nt] = prm[nt * 16 + m15];
    sh1[nt] = prm[32 + nt * 16 + m15];
  }
#pragma unroll
  for (int nt = 0; nt < 4; ++nt) {
    s2[nt] = prm[64 + nt * 16 + m15];
    sh2[nt] = prm[128 + nt * 16 + m15];
  }

  // ---- conv1: 36 m-tiles of 16 q-pixels; 3 MFMAs per n-tile (AhBh+AlBh+AhBl) ----
#pragma unroll 1
  for (int mt = 0; mt < 36; ++mt) {
    const int q = mt * 16 + m15;
    const int p_pool = q >> 2, sub = q & 3;
    const int py = p_pool / 12, px = p_pool - py * 12;
    const int Y = 2 * py + (sub >> 1), X = 2 * px + (sub & 1);
    const float* pixb = imgf + Y * 28 + X;
    float v[8];
#pragma unroll
    for (int j = 0; j < 8; ++j) v[j] = pixb[off[j]];
    uint4v hv, lv;
#pragma unroll
    for (int k = 0; k < 4; ++k) {
      const unsigned u0 = __float_as_uint(v[2 * k]);
      const unsigned u1 = __float_as_uint(v[2 * k + 1]);
      hv[k] = (u0 >> 16) | (u1 & 0xffff0000u);
      const float r0 = v[2 * k] - __uint_as_float(u0 & 0xffff0000u);
      const float r1 = v[2 * k + 1] - __uint_as_float(u1 & 0xffff0000u);
      lv[k] = (__float_as_uint(r0) >> 16) | (__float_as_uint(r1) & 0xffff0000u);
    }
    const short8_t ah = __builtin_bit_cast(short8_t, hv);
    const short8_t al = __builtin_bit_cast(short8_t, lv);

    f32x4 c0 = {0.f, 0.f, 0.f, 0.f}, c1 = {0.f, 0.f, 0.f, 0.f};
    c0 = __builtin_amdgcn_mfma_f32_16x16x32_bf16(ah, B1h[0], c0, 0, 0, 0);
    c1 = __builtin_amdgcn_mfma_f32_16x16x32_bf16(ah, B1h[1], c1, 0, 0, 0);
    c0 = __builtin_amdgcn_mfma_f32_16x16x32_bf16(al, B1h[0], c0, 0, 0, 0);
    c1 = __builtin_amdgcn_mfma_f32_16x16x32_bf16(al, B1h[1], c1, 0, 0, 0);
    c0 = __builtin_amdgcn_mfma_f32_16x16x32_bf16(ah, B1l[0], c0, 0, 0, 0);
    c1 = __builtin_amdgcn_mfma_f32_16x16x32_bf16(ah, B1l[1], c1, 0, 0, 0);

    // epilogue: 4 regs = 2x2 pool window (q-order); bn+relu; hi/lo -> insA
    const int cell = mt * 4 + g;
#pragma unroll
    for (int nt = 0; nt < 2; ++nt) {
      const f32x4 c = nt ? c1 : c0;
      const float pv = fmaxf(fmaxf(c[0], c[1]), fmaxf(c[2], c[3]));
      const float a = fmaxf(fmaf(pv, s1[nt], sh1[nt]), 0.f);
      const unsigned u = __float_as_uint(a);
      const float r = a - __uint_as_float(u & 0xffff0000u);
      const int ic = nt * 16 + m15;
      insA[cell * 40 + ic] = (ushort_t)(u >> 16);
      insA[5760 + cell * 40 + ic] = (ushort_t)(__float_as_uint(r) >> 16);
    }
  }

  // ---- conv2: wave owns all 4 oc-tiles; 5 ky-passes with 20 register B-frags each ----
  const int sy = (m15 & 3) >> 1, sx = m15 & 1;
  const int X2 = 2 * (m15 >> 2) + sx;

  f32x4 acc[4][4];
#pragma unroll
  for (int mt2 = 0; mt2 < 4; ++mt2)
#pragma unroll
    for (int nt = 0; nt < 4; ++nt) acc[mt2][nt] = (f32x4){0.f, 0.f, 0.f, 0.f};

#pragma unroll 1
  for (int pass = 0; pass < 5; ++pass) {
    short8_t wr[5][4];
#pragma unroll
    for (int kx = 0; kx < 5; ++kx)
#pragma unroll
      for (int nt = 0; nt < 4; ++nt)
        wr[kx][nt] = *(const short8_t*)(w2frag + (size_t)(((pass * 5 + kx) * 4 + nt) * 64 + l) * 8);
#pragma unroll
    for (int kx = 0; kx < 5; ++kx) {
#pragma unroll
      for (int mt2 = 0; mt2 < 4; ++mt2) {
        const int cellin = (2 * mt2 + sy + pass) * 12 + X2 + kx;
        const short8_t aH = *(const short8_t*)(insA + cellin * 40 + g * 8);
        const short8_t aL = *(const short8_t*)(insA + 5760 + cellin * 40 + g * 8);
#pragma unroll
        for (int nt = 0; nt < 4; ++nt) {
          acc[mt2][nt] = __builtin_amdgcn_mfma_f32_16x16x32_bf16(aH, wr[kx][nt], acc[mt2][nt], 0, 0, 0);
          acc[mt2][nt] = __builtin_amdgcn_mfma_f32_16x16x32_bf16(aL, wr[kx][nt], acc[mt2][nt], 0, 0, 0);
        }
      }
    }
  }

  // ---- conv2 epilogue: in-lane 2x2 pool, bn2+relu, hi/lo -> h2p ----
  const size_t ob = (size_t)b * 1024;
#pragma unroll
  for (int mt2 = 0; mt2 < 4; ++mt2) {
    const int cell2 = mt2 * 4 + g;
#pragma unroll
    for (int nt = 0; nt < 4; ++nt) {
      const f32x4 c = acc[mt2][nt];
      const float pv = fmaxf(fmaxf(c[0], c[1]), fmaxf(c[2], c[3]));
      const float a = fmaxf(fmaf(pv, s2[nt], sh2[nt]), 0.f);
      const unsigned u = __float_as_uint(a);
      const float r = a - __uint_as_float(u & 0xffff0000u);
      const int oc = nt * 16 + m15;
      h2pH[ob + oc * 16 + cell2] = (ushort_t)(u >> 16);
      h2pL[ob + oc * 16 + cell2] = (ushort_t)(__float_as_uint(r) >> 16);
    }
  }
}

// ---------------- fc3 (1024->512) + bn3 + relu via bf16 MFMA, no LDS ----------------
// grid (8,128); XCD-chunked swizzle: the 8 N-blocks sharing an A-panel -> same XCD L2
__launch_bounds__(256)
__global__ void fc3_kernel(const ushort_t* __restrict__ h2pH, const ushort_t* __restrict__ h2pL,
                           const ushort_t* __restrict__ w3frag, const float* __restrict__ prm,
                           float* __restrict__ a3) {
  const int orig = blockIdx.x + (blockIdx.y << 3);
  const int xcd = orig & 7;
  const int j = orig >> 3;
  const int ytile = (xcd << 4) | (j >> 3);
  const int xtile = j & 7;
  const int n0 = xtile * 64;
  const int m0 = ytile * 64;
  const int w = threadIdx.x >> 6, l = threadIdx.x & 63;
  const int mrow = m0 + w * 16 + (l & 15);
  const int kc8 = (l >> 4) * 8;

  const ushort_t* aHp = h2pH + (size_t)mrow * 1024 + kc8;
  const ushort_t* aLp = h2pL + (size_t)mrow * 1024 + kc8;
  const ushort_t* bp = w3frag + (size_t)(n0 >> 4) * 512 + (size_t)l * 8;

  f32x4 accH[4], accL[4];
#pragma unroll
  for (int t = 0; t < 4; ++t) {
    accH[t] = (f32x4){0.f, 0.f, 0.f, 0.f};
    accL[t] = (f32x4){0.f, 0.f, 0.f, 0.f};
  }

#pragma unroll 2
  for (int ks = 0; ks < 32; ++ks) {
    const short8_t aH = *(const short8_t*)(aHp + ks * 32);
    const short8_t aL = *(const short8_t*)(aLp + ks * 32);
    const ushort_t* bks = bp + (size_t)ks * 16384;
#pragma unroll
    for (int t = 0; t < 4; ++t) {
      const short8_t bb = *(const short8_t*)(bks + t * 512);
      accH[t] = __builtin_amdgcn_mfma_f32_16x16x32_bf16(aH, bb, accH[t], 0, 0, 0);
      accL[t] = __builtin_amdgcn_mfma_f32_16x16x32_bf16(aL, bb, accL[t], 0, 0, 0);
    }
  }

#pragma unroll
  for (int t = 0; t < 4; ++t) {
    const int oc = n0 + t * 16 + (l & 15);
    const float s = prm[192 + oc], sh = prm[704 + oc];
#pragma unroll
    for (int r = 0; r < 4; ++r) {
      const int m = m0 + w * 16 + (l >> 4) * 4 + r;
      a3[(size_t)m * 512 + oc] = fmaxf(fmaf(accH[t][r] + accL[t][r], s, sh), 0.f);
    }
  }
}

// ---------------- fc4 (512->10), one wave per batch row ----------------
__launch_bounds__(256)
__global__ void fc4_kernel(const float* __restrict__ a3, const float* __restrict__ w4,
                           float* __restrict__ out, int B) {
  const int w = threadIdx.x >> 6, l = threadIdx.x & 63;
  const int b = blockIdx.x * 4 + w;
  if (b >= B) return;
  const float4* ar = (const float4*)(a3 + (size_t)b * 512);
  const float4 a0 = ar[l * 2];
  const float4 a1 = ar[l * 2 + 1];
#pragma unroll
  for (int j = 0; j < 10; ++j) {
    const float4* wr = (const float4*)(w4 + j * 512);
    const float4 w0 = wr[l * 2];
    const float4 w1 = wr[l * 2 + 1];
    float sv = a0.x * w0.x + a0.y * w0.y + a0.z * w0.z + a0.w * w0.w +
               a1.x * w1.x + a1.y * w1.y + a1.z * w1.z + a1.w * w1.w;
#pragma unroll
    for (int off = 1; off < 64; off <<= 1) sv += __shfl_xor(sv, off);
    if (l == 0) out[(size_t)b * 10 + j] = sv;
  }
}

extern "C" void kernel_launch(void* const* d_in, const int* in_sizes, int n_in,
                              void* d_out, int out_size, void* d_ws, size_t ws_size,
                              hipStream_t stream) {
  const float* x  = (const float*)d_in[0];
  const float* w1 = (const float*)d_in[1];
  const float* b1 = (const float*)d_in[2];
  const float* g1 = (const float*)d_in[3];
  const float* be1 = (const float*)d_in[4];
  const float* m1 = (const float*)d_in[5];
  const float* v1 = (const float*)d_in[6];
  const float* w2 = (const float*)d_in[7];
  const float* b2 = (const float*)d_in[8];
  const float* g2 = (const float*)d_in[9];
  const float* be2 = (const float*)d_in[10];
  const float* m2 = (const float*)d_in[11];
  const float* v2 = (const float*)d_in[12];
  const float* w3 = (const float*)d_in[13];
  const float* b3 = (const float*)d_in[14];
  const float* g3 = (const float*)d_in[15];
  const float* be3 = (const float*)d_in[16];
  const float* m3 = (const float*)d_in[17];
  const float* v3 = (const float*)d_in[18];
  const float* w4 = (const float*)d_in[19];

  const int B = in_sizes[0] / 784;  // 8192

  float* prm = (float*)d_ws;                          // 1216 f32
  ushort_t* w1frag = (ushort_t*)(prm + 1216);         // 2048
  ushort_t* w2frag = w1frag + 2048;                   // 51200
  ushort_t* w3frag = w2frag + 51200;                  // 524288
  ushort_t* h2pH = w3frag + 524288;                   // B*1024
  ushort_t* h2pL = h2pH + (size_t)B * 1024;           // B*1024
  float* a3 = (float*)(h2pL + (size_t)B * 1024);      // B*512 f32

  prep_kernel<<<64, 256, 0, stream>>>(b1, g1, be1, m1, v1, b2, g2, be2, m2, v2,
                                      b3, g3, be3, m3, v3, w1, w2, w3,
                                      w1frag, w2frag, w3frag, prm);
  conv12_kernel<<<B / 2, 128, 0, stream>>>(x, w1frag, w2frag, prm, h2pH, h2pL);
  dim3 g3d(8, B / 64);
  fc3_kernel<<<g3d, 256, 0, stream>>>(h2pH, h2pL, w3frag, prm, a3);
  fc4_kernel<<<(B + 3) / 4, 256, 0, stream>>>(a3, w4, (float*)d_out, B);
}

// Round 6
// 283.144 us; speedup vs baseline: 2.4099x; 1.1307x over previous
//
#include <hip/hip_runtime.h>

#define EPS 1e-5f

typedef float f32x4 __attribute__((ext_vector_type(4)));
typedef short short8_t __attribute__((ext_vector_type(8)));
typedef unsigned int uint4v __attribute__((ext_vector_type(4)));
typedef unsigned short ushort_t;

// ---------------- prep: fold BN(+bias), build bf16 weight fragments ----------------
// prm (floats): [0..31] s1, [32..63] sh1, [64..127] s2, [128..191] sh2,
//               [192..703] s3, [704..1215] sh3
// w1frag (ushort): [plane=2][nt=2][lane=64][j=8]; oc=nt*16+(l&15), tap=(l>>4)*8+j (0 if tap>=25)
// w2frag (ushort): [kk=25][nt=4][lane=64][j=8]; oc=nt*16+(l&15), ic=(l>>4)*8+j
// w3frag (ushort): [ks=32][ntg=32][lane=64][j=8]; oc=ntg*16+(l&15), k=ks*32+(l>>4)*8+j
__global__ void prep_kernel(const float* __restrict__ b1, const float* __restrict__ g1,
                            const float* __restrict__ be1, const float* __restrict__ m1,
                            const float* __restrict__ v1,
                            const float* __restrict__ b2, const float* __restrict__ g2,
                            const float* __restrict__ be2, const float* __restrict__ m2,
                            const float* __restrict__ v2,
                            const float* __restrict__ b3, const float* __restrict__ g3,
                            const float* __restrict__ be3, const float* __restrict__ m3,
                            const float* __restrict__ v3,
                            const float* __restrict__ w1, const float* __restrict__ w2,
                            const float* __restrict__ w3,
                            ushort_t* __restrict__ w1frag, ushort_t* __restrict__ w2frag,
                            ushort_t* __restrict__ w3frag, float* __restrict__ prm) {
  int tid = blockIdx.x * blockDim.x + threadIdx.x;
  int stride = gridDim.x * blockDim.x;
  for (int c = tid; c < 32; c += stride) {
    float s = g1[c] / sqrtf(v1[c] + EPS);
    prm[c] = s;
    prm[32 + c] = (b1[c] - m1[c]) * s + be1[c];
  }
  for (int c = tid; c < 64; c += stride) {
    float s = g2[c] / sqrtf(v2[c] + EPS);
    prm[64 + c] = s;
    prm[128 + c] = (b2[c] - m2[c]) * s + be2[c];
  }
  for (int c = tid; c < 512; c += stride) {
    float s = g3[c] / sqrtf(v3[c] + EPS);
    prm[192 + c] = s;
    prm[704 + c] = (b3[c] - m3[c]) * s + be3[c];
  }
  // w1frag: hi/lo planes (w1 is NOT ternary)
  for (int i = tid; i < 2 * 2 * 64 * 8; i += stride) {
    const int j = i & 7;
    const int l = (i >> 3) & 63;
    const int nt = (i >> 9) & 1;
    const int p = i >> 10;
    const int oc = nt * 16 + (l & 15);
    const int t = (l >> 4) * 8 + j;
    const float v = (t < 25) ? w1[oc * 25 + t] : 0.f;
    const unsigned u = __float_as_uint(v);
    const ushort_t hi = (ushort_t)(u >> 16);
    const float r = v - __uint_as_float(u & 0xffff0000u);
    const ushort_t lo = (ushort_t)(__float_as_uint(r) >> 16);
    w1frag[i] = p ? lo : hi;
  }
  // w2: [64][32][5][5]; ternary -> bf16 truncation exact
  for (int i = tid; i < 25 * 4 * 64 * 8; i += stride) {
    const int kk = i >> 11;
    const int r = i & 2047;
    const int nt = r >> 9;
    const int r2 = r & 511;
    const int l = r2 >> 3;
    const int j = r2 & 7;
    const int oc = nt * 16 + (l & 15);
    const int ic = (l >> 4) * 8 + j;
    w2frag[i] = (ushort_t)(__float_as_uint(w2[oc * 800 + ic * 25 + kk]) >> 16);
  }
  // w3: [512][1024] ternary
  for (int i = tid; i < 32 * 32 * 64 * 8; i += stride) {
    const int ks = i >> 14;
    const int r = i & 16383;
    const int ntg = r >> 9;
    const int r2 = r & 511;
    const int l = r2 >> 3;
    const int j = r2 & 7;
    const int oc = ntg * 16 + (l & 15);
    const int k = ks * 32 + (l >> 4) * 8 + j;
    w3frag[i] = (ushort_t)(__float_as_uint(w3[oc * 1024 + k]) >> 16);
  }
}

// ---------------- fused conv1+bn1+relu+pool1 + conv2+bn2+relu+pool2, all MFMA ----------------
// Block = 128 threads = 2 waves sharing ONE image (one 26.2 KB arena -> 6 blocks/CU,
// 12 waves/CU). conv1: wave w does m-tiles w*18..w*18+17 (all 32 ocs). conv2: wave w
// does pixel-tiles mt2 in {2w,2w+1} x all 4 oc-tiles (A-reads per image unchanged).
// insA cell stride 80 B keeps the ds_read_b128 pattern conflict-free/2-way.
// q-ordering (q = cell*4 + sub) makes each C-fragment's 4 regs = one 2x2 pool window.
__launch_bounds__(128)
__global__ void conv12_kernel(const float* __restrict__ x,
                              const ushort_t* __restrict__ w1frag,
                              const ushort_t* __restrict__ w2frag,
                              const float* __restrict__ prm,
                              ushort_t* __restrict__ h2pH, ushort_t* __restrict__ h2pL) {
  __shared__ __align__(16) unsigned char lds[26240];

  const int tid = threadIdx.x;
  const int w = tid >> 6, l = tid & 63;
  const int b = blockIdx.x;
  const int m15 = l & 15, g = l >> 4;

  float* imgf = (float*)lds;                        // 800 f32
  ushort_t* insA = (ushort_t*)(lds + 3200);         // 2 planes x 144 cells x 40 ushorts

  // --- stage the image into LDS (both waves) ---
  const float* xb = x + (size_t)b * 784;
  for (int i = tid; i < 196; i += 128) ((float4*)imgf)[i] = ((const float4*)xb)[i];
  if (tid < 16) imgf[784 + tid] = 0.f;

  // --- conv1 B-frags (hi/lo), 16 VGPRs ---
  short8_t B1h[2], B1l[2];
#pragma unroll
  for (int nt = 0; nt < 2; ++nt) {
    B1h[nt] = *(const short8_t*)(w1frag + (size_t)(nt * 64 + l) * 8);
    B1l[nt] = *(const short8_t*)(w1frag + (size_t)((2 + nt) * 64 + l) * 8);
  }

  // per-lane tap offsets for this lane's k-group (fake taps clamped; B=0 there)
  int off[8];
#pragma unroll
  for (int j = 0; j < 8; ++j) {
    const int t = g * 8 + j;
    const int ky = t / 5, kx = t - ky * 5;
    off[j] = (t < 25) ? (ky * 28 + kx) : 0;
  }

  // BN params in regs
  float s1[2], sh1[2], s2[4], sh2[4];
#pragma unroll
  for (int nt = 0; nt < 2; ++nt) {
    s1[nt] = prm[nt * 16 + m15];
    sh1[nt] = prm[32 + nt * 16 + m15];
  }
#pragma unroll
  for (int nt = 0; nt < 4; ++nt) {
    s2[nt] = prm[64 + nt * 16 + m15];
    sh2[nt] = prm[128 + nt * 16 + m15];
  }
  __syncthreads();

  // ---- conv1: 18 m-tiles per wave; 3 MFMAs per n-tile (AhBh+AlBh+AhBl) ----
#pragma unroll 1
  for (int i = 0; i < 18; ++i) {
    const int mt = w * 18 + i;
    const int q = mt * 16 + m15;
    const int p_pool = q >> 2, sub = q & 3;
    const int py = p_pool / 12, px = p_pool - py * 12;
    const int Y = 2 * py + (sub >> 1), X = 2 * px + (sub & 1);
    const float* pixb = imgf + Y * 28 + X;
    float v[8];
#pragma unroll
    for (int j = 0; j < 8; ++j) v[j] = pixb[off[j]];
    uint4v hv, lv;
#pragma unroll
    for (int k = 0; k < 4; ++k) {
      const unsigned u0 = __float_as_uint(v[2 * k]);
      const unsigned u1 = __float_as_uint(v[2 * k + 1]);
      hv[k] = (u0 >> 16) | (u1 & 0xffff0000u);
      const float r0 = v[2 * k] - __uint_as_float(u0 & 0xffff0000u);
      const float r1 = v[2 * k + 1] - __uint_as_float(u1 & 0xffff0000u);
      lv[k] = (__float_as_uint(r0) >> 16) | (__float_as_uint(r1) & 0xffff0000u);
    }
    const short8_t ah = __builtin_bit_cast(short8_t, hv);
    const short8_t al = __builtin_bit_cast(short8_t, lv);

    f32x4 c0 = {0.f, 0.f, 0.f, 0.f}, c1 = {0.f, 0.f, 0.f, 0.f};
    c0 = __builtin_amdgcn_mfma_f32_16x16x32_bf16(ah, B1h[0], c0, 0, 0, 0);
    c1 = __builtin_amdgcn_mfma_f32_16x16x32_bf16(ah, B1h[1], c1, 0, 0, 0);
    c0 = __builtin_amdgcn_mfma_f32_16x16x32_bf16(al, B1h[0], c0, 0, 0, 0);
    c1 = __builtin_amdgcn_mfma_f32_16x16x32_bf16(al, B1h[1], c1, 0, 0, 0);
    c0 = __builtin_amdgcn_mfma_f32_16x16x32_bf16(ah, B1l[0], c0, 0, 0, 0);
    c1 = __builtin_amdgcn_mfma_f32_16x16x32_bf16(ah, B1l[1], c1, 0, 0, 0);

    // epilogue: 4 regs = 2x2 pool window (q-order); bn+relu; hi/lo -> insA
    const int cell = mt * 4 + g;
#pragma unroll
    for (int nt = 0; nt < 2; ++nt) {
      const f32x4 c = nt ? c1 : c0;
      const float pv = fmaxf(fmaxf(c[0], c[1]), fmaxf(c[2], c[3]));
      const float a = fmaxf(fmaf(pv, s1[nt], sh1[nt]), 0.f);
      const unsigned u = __float_as_uint(a);
      const float r = a - __uint_as_float(u & 0xffff0000u);
      const int ic = nt * 16 + m15;
      insA[cell * 40 + ic] = (ushort_t)(u >> 16);
      insA[5760 + cell * 40 + ic] = (ushort_t)(__float_as_uint(r) >> 16);
    }
  }
  __syncthreads();

  // ---- conv2: wave owns pixel-tiles {2w, 2w+1} x all 4 oc-tiles; 5 ky-passes ----
  const int sy = (m15 & 3) >> 1, sx = m15 & 1;
  const int X2 = 2 * (m15 >> 2) + sx;

  f32x4 acc[2][4];
#pragma unroll
  for (int m = 0; m < 2; ++m)
#pragma unroll
    for (int nt = 0; nt < 4; ++nt) acc[m][nt] = (f32x4){0.f, 0.f, 0.f, 0.f};

#pragma unroll 1
  for (int pass = 0; pass < 5; ++pass) {
    short8_t wr[5][4];
#pragma unroll
    for (int kx = 0; kx < 5; ++kx)
#pragma unroll
      for (int nt = 0; nt < 4; ++nt)
        wr[kx][nt] = *(const short8_t*)(w2frag + (size_t)(((pass * 5 + kx) * 4 + nt) * 64 + l) * 8);
#pragma unroll
    for (int kx = 0; kx < 5; ++kx) {
#pragma unroll
      for (int m = 0; m < 2; ++m) {
        const int mt2 = 2 * w + m;
        const int cellin = (2 * mt2 + sy + pass) * 12 + X2 + kx;
        const short8_t aH = *(const short8_t*)(insA + cellin * 40 + g * 8);
        const short8_t aL = *(const short8_t*)(insA + 5760 + cellin * 40 + g * 8);
#pragma unroll
        for (int nt = 0; nt < 4; ++nt) {
          acc[m][nt] = __builtin_amdgcn_mfma_f32_16x16x32_bf16(aH, wr[kx][nt], acc[m][nt], 0, 0, 0);
          acc[m][nt] = __builtin_amdgcn_mfma_f32_16x16x32_bf16(aL, wr[kx][nt], acc[m][nt], 0, 0, 0);
        }
      }
    }
  }

  // ---- conv2 epilogue: in-lane 2x2 pool, bn2+relu, hi/lo -> h2p ----
  const size_t ob = (size_t)b * 1024;
#pragma unroll
  for (int m = 0; m < 2; ++m) {
    const int cell2 = (2 * w + m) * 4 + g;
#pragma unroll
    for (int nt = 0; nt < 4; ++nt) {
      const f32x4 c = acc[m][nt];
      const float pv = fmaxf(fmaxf(c[0], c[1]), fmaxf(c[2], c[3]));
      const float a = fmaxf(fmaf(pv, s2[nt], sh2[nt]), 0.f);
      const unsigned u = __float_as_uint(a);
      const float r = a - __uint_as_float(u & 0xffff0000u);
      const int oc = nt * 16 + m15;
      h2pH[ob + oc * 16 + cell2] = (ushort_t)(u >> 16);
      h2pL[ob + oc * 16 + cell2] = (ushort_t)(__float_as_uint(r) >> 16);
    }
  }
}

// ---------------- fc3 (1024->512) + bn3 + relu via bf16 MFMA, no LDS ----------------
// grid (8,128); XCD-chunked swizzle: the 8 N-blocks sharing an A-panel -> same XCD L2
__launch_bounds__(256)
__global__ void fc3_kernel(const ushort_t* __restrict__ h2pH, const ushort_t* __restrict__ h2pL,
                           const ushort_t* __restrict__ w3frag, const float* __restrict__ prm,
                           float* __restrict__ a3) {
  const int orig = blockIdx.x + (blockIdx.y << 3);
  const int xcd = orig & 7;
  const int j = orig >> 3;
  const int ytile = (xcd << 4) | (j >> 3);
  const int xtile = j & 7;
  const int n0 = xtile * 64;
  const int m0 = ytile * 64;
  const int w = threadIdx.x >> 6, l = threadIdx.x & 63;
  const int mrow = m0 + w * 16 + (l & 15);
  const int kc8 = (l >> 4) * 8;

  const ushort_t* aHp = h2pH + (size_t)mrow * 1024 + kc8;
  const ushort_t* aLp = h2pL + (size_t)mrow * 1024 + kc8;
  const ushort_t* bp = w3frag + (size_t)(n0 >> 4) * 512 + (size_t)l * 8;

  f32x4 accH[4], accL[4];
#pragma unroll
  for (int t = 0; t < 4; ++t) {
    accH[t] = (f32x4){0.f, 0.f, 0.f, 0.f};
    accL[t] = (f32x4){0.f, 0.f, 0.f, 0.f};
  }

#pragma unroll 2
  for (int ks = 0; ks < 32; ++ks) {
    const short8_t aH = *(const short8_t*)(aHp + ks * 32);
    const short8_t aL = *(const short8_t*)(aLp + ks * 32);
    const ushort_t* bks = bp + (size_t)ks * 16384;
#pragma unroll
    for (int t = 0; t < 4; ++t) {
      const short8_t bb = *(const short8_t*)(bks + t * 512);
      accH[t] = __builtin_amdgcn_mfma_f32_16x16x32_bf16(aH, bb, accH[t], 0, 0, 0);
      accL[t] = __builtin_amdgcn_mfma_f32_16x16x32_bf16(aL, bb, accL[t], 0, 0, 0);
    }
  }

#pragma unroll
  for (int t = 0; t < 4; ++t) {
    const int oc = n0 + t * 16 + (l & 15);
    const float s = prm[192 + oc], sh = prm[704 + oc];
#pragma unroll
    for (int r = 0; r < 4; ++r) {
      const int m = m0 + w * 16 + (l >> 4) * 4 + r;
      a3[(size_t)m * 512 + oc] = fmaxf(fmaf(accH[t][r] + accL[t][r], s, sh), 0.f);
    }
  }
}

// ---------------- fc4 (512->10), one wave per batch row ----------------
__launch_bounds__(256)
__global__ void fc4_kernel(const float* __restrict__ a3, const float* __restrict__ w4,
                           float* __restrict__ out, int B) {
  const int w = threadIdx.x >> 6, l = threadIdx.x & 63;
  const int b = blockIdx.x * 4 + w;
  if (b >= B) return;
  const float4* ar = (const float4*)(a3 + (size_t)b * 512);
  const float4 a0 = ar[l * 2];
  const float4 a1 = ar[l * 2 + 1];
#pragma unroll
  for (int j = 0; j < 10; ++j) {
    const float4* wr = (const float4*)(w4 + j * 512);
    const float4 w0 = wr[l * 2];
    const float4 w1 = wr[l * 2 + 1];
    float sv = a0.x * w0.x + a0.y * w0.y + a0.z * w0.z + a0.w * w0.w +
               a1.x * w1.x + a1.y * w1.y + a1.z * w1.z + a1.w * w1.w;
#pragma unroll
    for (int off = 1; off < 64; off <<= 1) sv += __shfl_xor(sv, off);
    if (l == 0) out[(size_t)b * 10 + j] = sv;
  }
}

extern "C" void kernel_launch(void* const* d_in, const int* in_sizes, int n_in,
                              void* d_out, int out_size, void* d_ws, size_t ws_size,
                              hipStream_t stream) {
  const float* x  = (const float*)d_in[0];
  const float* w1 = (const float*)d_in[1];
  const float* b1 = (const float*)d_in[2];
  const float* g1 = (const float*)d_in[3];
  const float* be1 = (const float*)d_in[4];
  const float* m1 = (const float*)d_in[5];
  const float* v1 = (const float*)d_in[6];
  const float* w2 = (const float*)d_in[7];
  const float* b2 = (const float*)d_in[8];
  const float* g2 = (const float*)d_in[9];
  const float* be2 = (const float*)d_in[10];
  const float* m2 = (const float*)d_in[11];
  const float* v2 = (const float*)d_in[12];
  const float* w3 = (const float*)d_in[13];
  const float* b3 = (const float*)d_in[14];
  const float* g3 = (const float*)d_in[15];
  const float* be3 = (const float*)d_in[16];
  const float* m3 = (const float*)d_in[17];
  const float* v3 = (const float*)d_in[18];
  const float* w4 = (const float*)d_in[19];

  const int B = in_sizes[0] / 784;  // 8192

  float* prm = (float*)d_ws;                          // 1216 f32
  ushort_t* w1frag = (ushort_t*)(prm + 1216);         // 2048
  ushort_t* w2frag = w1frag + 2048;                   // 51200
  ushort_t* w3frag = w2frag + 51200;                  // 524288
  ushort_t* h2pH = w3frag + 524288;                   // B*1024
  ushort_t* h2pL = h2pH + (size_t)B * 1024;           // B*1024
  float* a3 = (float*)(h2pL + (size_t)B * 1024);      // B*512 f32

  prep_kernel<<<64, 256, 0, stream>>>(b1, g1, be1, m1, v1, b2, g2, be2, m2, v2,
                                      b3, g3, be3, m3, v3, w1, w2, w3,
                                      w1frag, w2frag, w3frag, prm);
  conv12_kernel<<<B, 128, 0, stream>>>(x, w1frag, w2frag, prm, h2pH, h2pL);
  dim3 g3d(8, B / 64);
  fc3_kernel<<<g3d, 256, 0, stream>>>(h2pH, h2pL, w3frag, prm, a3);
  fc4_kernel<<<(B + 3) / 4, 256, 0, stream>>>(a3, w4, (float*)d_out, B);
}